// Round 23
// baseline (64.543 us; speedup 1.0000x reference)
//
#include <hip/hip_runtime.h>
#include <math.h>

#define BATCH 32
#define NN 1024
#define FF 128
#define HH 128
#define NODES 32   // nodes per block in kernel A

typedef __attribute__((ext_vector_type(8))) short short8v;   // 8 bf16
typedef __attribute__((ext_vector_type(4))) float f32x4;     // MFMA acc

__device__ __forceinline__ unsigned short f2bf(float f) {    // RNE f32->bf16
    unsigned u = __float_as_uint(f);
    u += 0x7fffu + ((u >> 16) & 1u);
    return (unsigned short)(u >> 16);
}

// ---------------- Kernel A: h = X@W -> g (MFMA-B-fragment-swizzled bf16);
// a_self / a_neigh scalars.  g[(batch,kc,ct,lane=kg*16+li,e)] = h[kc*32+kg*8+e][ct*16+li]
__global__ __launch_bounds__(128) void gat_hidden(
    const float* __restrict__ X,      // [B,N,F]
    const float* __restrict__ W,      // [F,H]
    const float* __restrict__ Wself,  // [H]
    const float* __restrict__ Wneigh, // [H]
    unsigned short* __restrict__ g,   // [B][32 kc][8 ct][64 lane][8] bf16
    float* __restrict__ a_self,       // [B*N]
    float* __restrict__ a_neigh)      // [B*N]
{
    __shared__ float xs[NODES][FF];      // 16 KB
    __shared__ float hs[NODES][HH + 1];  // 16.5 KB
    const int tid = threadIdx.x;
    const long base_node = (long)blockIdx.x * NODES;
    const int batch = (int)(base_node >> 10);
    const int kc = (int)((base_node & 1023) >> 5);   // 32-node chunk index

    const float4* X4 = (const float4*)(X + base_node * FF);
    float4* xs4 = (float4*)&xs[0][0];
#pragma unroll
    for (int k = 0; k < (NODES * FF) / (4 * 128); k++)
        xs4[k * 128 + tid] = X4[k * 128 + tid];
    __syncthreads();

    float acc[NODES];
#pragma unroll
    for (int n = 0; n < NODES; n++) acc[n] = 0.f;
    const int c = tid;
    for (int fq = 0; fq < FF / 4; fq++) {
        const float w0 = W[(4 * fq + 0) * HH + c];
        const float w1 = W[(4 * fq + 1) * HH + c];
        const float w2 = W[(4 * fq + 2) * HH + c];
        const float w3 = W[(4 * fq + 3) * HH + c];
#pragma unroll
        for (int n = 0; n < NODES; n++) {
            const float4 x4 = *(const float4*)&xs[n][4 * fq];
            acc[n] += x4.x * w0 + x4.y * w1 + x4.z * w2 + x4.w * w3;
        }
    }
    {
        const int ct = c >> 4, li = c & 15;
        unsigned short* gb = g + ((((size_t)batch * 32 + kc) * 8 + ct) * 64) * 8;
        union { uint4 q; unsigned short u[8]; } pk;
#pragma unroll
        for (int kg = 0; kg < 4; kg++) {
#pragma unroll
            for (int e = 0; e < 8; e++) pk.u[e] = f2bf(acc[kg * 8 + e]);
            *(uint4*)(gb + (kg * 16 + li) * 8) = pk.q;
        }
    }
#pragma unroll
    for (int n = 0; n < NODES; n++) hs[n][c] = acc[n];
    __syncthreads();

    if (tid < 2 * NODES) {
        const int n = tid & (NODES - 1);
        const float* wvp = (tid < NODES) ? Wself : Wneigh;
        float s = 0.f;
        for (int cc = 0; cc < HH; cc++) s += hs[n][cc] * wvp[cc];
        if (tid < NODES) a_self[base_node + n] = s;
        else             a_neigh[base_node + n] = s;
    }
}

// ---------------- Kernel B: P@H via MFMA, A-fragment built IN REGISTERS.
// Wave = 16-row tile x K-half(512). Lane (kg,li) computes p[row li][kg*8+e]
// directly: adj bytes for the 4 kg-lanes of a row sit in ONE 128B line ->
// 16 fully-consumed lines per wave-load (coalescing-equivalent). No LDS ops,
// no barriers in the loop; one end-barrier combines K-halves via LDS.
// Numerics identical to R19/R21: unnormalized exp, rowsum of bf16-ROUNDED p.
__global__ __launch_bounds__(256) void gat_attend(
    const float* __restrict__ adj,     // [B,N,N]
    const float* __restrict__ mask,    // [B,N]
    const unsigned short* __restrict__ g, // swizzled bf16 h
    const float* __restrict__ a_self,  // [B*N]
    const float* __restrict__ a_neigh, // [B*N]
    const float* __restrict__ bvec,    // [H]
    float* __restrict__ out)           // [B,N,H]
{
    const int tid = threadIdx.x;
    const int lane = tid & 63;
    const int wv = tid >> 6;                 // 0..3
    // 1024 blocks; XCD x owns 4 batches; block = 2 row-tiles x 2 K-halves
    const int b = blockIdx.x;
    const int xcd = b & 7;
    const int rest = b >> 3;                 // 0..127
    const int batch = xcd * 4 + (rest >> 5);
    const int q = rest & 31;                 // 0..31 (pair of 16-row tiles)
    const int tsel = wv >> 1;                // which tile of the pair
    const int kh = wv & 1;                   // K-half
    const int tile = q * 2 + tsel;           // 0..63
    const int r0 = batch * NN + tile * 16;

    if (mask[batch * NN + q * 32] == 0.f) {  // block-uniform (768 % 32 == 0)
        float4* o4 = (float4*)(out + (size_t)(batch * NN + q * 32) * HH);
#pragma unroll
        for (int k = 0; k < 4; k++)
            o4[k * 256 + tid] = make_float4(0.f, 0.f, 0.f, 0.f);
        return;
    }

    __shared__ f32x4 accs[2][8][64];         // K-half-1 partials, 16 KB
    __shared__ float rs1_lds[2][16];

    const int li = lane & 15;                // A row / B,D col
    const int kg8 = (lane >> 4) * 8;         // k-slice base
    const float* arow = adj + (size_t)(r0 + li) * NN + kh * 512 + kg8;
    const float* anp  = a_neigh + (size_t)batch * NN + kh * 512 + kg8;
    const float asl = a_self[r0 + li];
    const unsigned short* gb = g + (size_t)batch * 131072;   // 32*8*64*8

    f32x4 acc[8];
#pragma unroll
    for (int ct = 0; ct < 8; ct++)
#pragma unroll
        for (int i = 0; i < 4; i++) acc[ct][i] = 0.f;
    float rs = 0.f;

    float4 Aa0, Aa1, Na0, Na1, Ab0, Ab1, Nb0, Nb1;  // 2-deep adj pipeline

#define LOADTO(t, A0, A1, N0, N1)                         \
    {                                                     \
        A0 = *(const float4*)(arow + (t) * 32);           \
        A1 = *(const float4*)(arow + (t) * 32 + 4);       \
        N0 = *(const float4*)(anp + (t) * 32);            \
        N1 = *(const float4*)(anp + (t) * 32 + 4);        \
    }
#define EWE(av, nv, idx)                                                   \
    {                                                                      \
        const float x = asl + (nv);                                        \
        const float p = ((av) > 0.f) ? __expf(fmaxf(x, 0.2f * x)) : 0.f;   \
        fa.u[idx] = f2bf(p);                                               \
        rs += __uint_as_float((unsigned)fa.u[idx] << 16);                  \
    }
    // chunk t: consume IN regs (adj chunk t), prefetch chunk t+1 into OUT regs
#define CHUNK(t, IA0, IA1, IN0, IN1, OA0, OA1, ON0, ON1)                   \
    {                                                                      \
        if ((t) < 15) LOADTO((t) + 1, OA0, OA1, ON0, ON1)                  \
        union { short8v v; unsigned short u[8]; } fa;                      \
        EWE(IA0.x, IN0.x, 0) EWE(IA0.y, IN0.y, 1)                          \
        EWE(IA0.z, IN0.z, 2) EWE(IA0.w, IN0.w, 3)                          \
        EWE(IA1.x, IN1.x, 4) EWE(IA1.y, IN1.y, 5)                          \
        EWE(IA1.z, IN1.z, 6) EWE(IA1.w, IN1.w, 7)                          \
        const int kcG = kh * 16 + (t);                                     \
        _Pragma("unroll")                                                  \
        for (int ct = 0; ct < 8; ct++) {                                   \
            const short8v bf = *(const short8v*)(gb + ((size_t)(kcG * 8 + ct) * 64 + lane) * 8); \
            acc[ct] = __builtin_amdgcn_mfma_f32_16x16x32_bf16(fa.v, bf, acc[ct], 0, 0, 0);       \
        }                                                                  \
    }

    LOADTO(0, Aa0, Aa1, Na0, Na1)
    for (int i2 = 0; i2 < 8; ++i2) {
        const int t0 = 2 * i2;
        CHUNK(t0,     Aa0, Aa1, Na0, Na1, Ab0, Ab1, Nb0, Nb1)
        CHUNK(t0 + 1, Ab0, Ab1, Nb0, Nb1, Aa0, Aa1, Na0, Na1)
    }

    // rowsum for this K-half: combine the 4 kg lanes of each row
    rs += __shfl_xor(rs, 16);
    rs += __shfl_xor(rs, 32);                // every lane: total for row li

    if (kh == 1) {                           // dump K-half-1 partials
#pragma unroll
        for (int ct = 0; ct < 8; ct++) accs[tsel][ct][lane] = acc[ct];
        if (lane < 16) rs1_lds[tsel][lane] = rs;
    }
    __syncthreads();

    if (kh == 0) {                           // combine, normalize, store
        const float invr = 1.f / (rs + rs1_lds[tsel][li]);
        float iv[4];
#pragma unroll
        for (int i = 0; i < 4; i++)
            iv[i] = __shfl(invr, (lane >> 4) * 4 + i);   // inv for D row
#pragma unroll
        for (int ct = 0; ct < 8; ct++) {
            const f32x4 pr = accs[tsel][ct][lane];
            const float bv = bvec[ct * 16 + li];
#pragma unroll
            for (int i = 0; i < 4; i++) {
                const int r = (lane >> 4) * 4 + i;       // D row in tile
                out[(size_t)(r0 + r) * HH + ct * 16 + li] =
                    (acc[ct][i] + pr[i]) * iv[i] + bv;
            }
        }
    }
#undef LOADTO
#undef EWE
#undef CHUNK
}

extern "C" void kernel_launch(void* const* d_in, const int* in_sizes, int n_in,
                              void* d_out, int out_size, void* d_ws, size_t ws_size,
                              hipStream_t stream) {
    const float* X      = (const float*)d_in[0];  // M_features [B,N,F]
    const float* adj    = (const float*)d_in[1];  // M_adjacency [B,N,N]
    const float* mask   = (const float*)d_in[2];  // [B,N]
    const float* W      = (const float*)d_in[3];  // [F,H]
    const float* bvec   = (const float*)d_in[4];  // [H]
    const float* Wself  = (const float*)d_in[5];  // [H,1]
    const float* Wneigh = (const float*)d_in[6];  // [H,1]
    float* out = (float*)d_out;

    char* wsb = (char*)d_ws;
    unsigned short* g = (unsigned short*)wsb;                // 8 MB
    float* a_self  = (float*)(wsb + (size_t)BATCH * NN * HH * 2);
    float* a_neigh = a_self + (size_t)BATCH * NN;

    gat_hidden<<<(BATCH * NN) / NODES, 128, 0, stream>>>(
        X, W, Wself, Wneigh, g, a_self, a_neigh);
    gat_attend<<<1024, 256, 0, stream>>>(
        adj, mask, g, a_self, a_neigh, bvec, out);
}

// Round 24
// 59.294 us; speedup vs baseline: 1.0885x; 1.0885x over previous
//
#include <hip/hip_runtime.h>
#include <math.h>

#define BATCH 32
#define NN 1024
#define FF 128
#define HH 128
#define NODES 32   // nodes per block in kernel A
#define PROW 136   // padded P-tile row (bf16) for K=128 chunks

typedef __attribute__((ext_vector_type(8))) short short8v;   // 8 bf16
typedef __attribute__((ext_vector_type(4))) float f32x4;     // MFMA acc

__device__ __forceinline__ unsigned short f2bf(float f) {    // RNE f32->bf16
    unsigned u = __float_as_uint(f);
    u += 0x7fffu + ((u >> 16) & 1u);
    return (unsigned short)(u >> 16);
}

// ---------------- Kernel A: h = X@W -> g (MFMA-B-fragment-swizzled bf16);
// a_self / a_neigh scalars.  g[(batch,kc,ct,lane=kg*16+li,e)] = h[kc*32+kg*8+e][ct*16+li]
__global__ __launch_bounds__(128) void gat_hidden(
    const float* __restrict__ X,      // [B,N,F]
    const float* __restrict__ W,      // [F,H]
    const float* __restrict__ Wself,  // [H]
    const float* __restrict__ Wneigh, // [H]
    unsigned short* __restrict__ g,   // [B][32 kc][8 ct][64 lane][8] bf16
    float* __restrict__ a_self,       // [B*N]
    float* __restrict__ a_neigh)      // [B*N]
{
    __shared__ float xs[NODES][FF];      // 16 KB
    __shared__ float hs[NODES][HH + 1];  // 16.5 KB
    const int tid = threadIdx.x;
    const long base_node = (long)blockIdx.x * NODES;
    const int batch = (int)(base_node >> 10);
    const int kc = (int)((base_node & 1023) >> 5);   // 32-node chunk index

    const float4* X4 = (const float4*)(X + base_node * FF);
    float4* xs4 = (float4*)&xs[0][0];
#pragma unroll
    for (int k = 0; k < (NODES * FF) / (4 * 128); k++)
        xs4[k * 128 + tid] = X4[k * 128 + tid];
    __syncthreads();

    float acc[NODES];
#pragma unroll
    for (int n = 0; n < NODES; n++) acc[n] = 0.f;
    const int c = tid;
    for (int fq = 0; fq < FF / 4; fq++) {
        const float w0 = W[(4 * fq + 0) * HH + c];
        const float w1 = W[(4 * fq + 1) * HH + c];
        const float w2 = W[(4 * fq + 2) * HH + c];
        const float w3 = W[(4 * fq + 3) * HH + c];
#pragma unroll
        for (int n = 0; n < NODES; n++) {
            const float4 x4 = *(const float4*)&xs[n][4 * fq];
            acc[n] += x4.x * w0 + x4.y * w1 + x4.z * w2 + x4.w * w3;
        }
    }
    {
        const int ct = c >> 4, li = c & 15;
        unsigned short* gb = g + ((((size_t)batch * 32 + kc) * 8 + ct) * 64) * 8;
        union { uint4 q; unsigned short u[8]; } pk;
#pragma unroll
        for (int kg = 0; kg < 4; kg++) {
#pragma unroll
            for (int e = 0; e < 8; e++) pk.u[e] = f2bf(acc[kg * 8 + e]);
            *(uint4*)(gb + (kg * 16 + li) * 8) = pk.q;
        }
    }
#pragma unroll
    for (int n = 0; n < NODES; n++) hs[n][c] = acc[n];
    __syncthreads();

    if (tid < 2 * NODES) {
        const int n = tid & (NODES - 1);
        const float* wvp = (tid < NODES) ? Wself : Wneigh;
        float s = 0.f;
        for (int cc = 0; cc < HH; cc++) s += hs[n][cc] * wvp[cc];
        if (tid < NODES) a_self[base_node + n] = s;
        else             a_neigh[base_node + n] = s;
    }
}

// ---------------- Kernel B: fused P@H (R21 geometry), K=128 per phase,
// drain-free barriers so prefetched loads SPAN phases (T4 mechanism).
// 64-row tiles, 8 waves, wave = one ct column x 4 row-tiles, full K.
// Body order: B-loads first (oldest -> MFMA waits vmcnt(8), prefetch alive),
// then adj/an prefetch for t+1, then ds_read+MFMA, then exp+pack+ds_write,
// then lgkmcnt(0)+s_barrier (NO vmcnt drain).
// Numerics identical to R19/R21: unnormalized exp, rowsum of bf16-ROUNDED p.
__global__ __launch_bounds__(512) void gat_attend(
    const float* __restrict__ adj,     // [B,N,N]
    const float* __restrict__ mask,    // [B,N]
    const unsigned short* __restrict__ g, // swizzled bf16 h
    const float* __restrict__ a_self,  // [B*N]
    const float* __restrict__ a_neigh, // [B*N]
    const float* __restrict__ bvec,    // [H]
    float* __restrict__ out)           // [B,N,H]
{
    const int tid = threadIdx.x;
    const int lane = tid & 63;
    const int wv = tid >> 6;                 // 0..7 = ct column
    // 512 blocks; XCD x owns 4 batches
    const int b = blockIdx.x;
    const int xcd = b & 7;
    const int rest = b >> 3;                 // 0..63
    const int batch = xcd * 4 + (rest >> 4);
    const int tile = rest & 15;              // 0..15 (64-row tiles)
    const int r0 = batch * NN + tile * 64;   // 768 % 64 == 0: tile uniform

    if (mask[r0] == 0.f) {                   // invalid tile: zero-fill out
        float4* o4 = (float4*)(out + (size_t)r0 * HH);
#pragma unroll
        for (int k = 0; k < 4; k++)
            o4[k * 512 + tid] = make_float4(0.f, 0.f, 0.f, 0.f);
        return;
    }

    __shared__ unsigned short P[2][64 * PROW];   // 34816 B
    __shared__ float rtot[64];                   // 256 B

    // staging: thread owns row srow (tid>>3); per phase 16 j's:
    // j = t*128 + k*32 + c8*4 + 0..3 for k=0..3 (c8-consecutive loads)
    const int srow = tid >> 3;               // 0..63
    const int c8 = tid & 7;
    const float4* arow = (const float4*)(adj + (size_t)(r0 + srow) * NN);
    const float4* anp = (const float4*)(a_neigh + (size_t)batch * NN);
    const float asl = a_self[r0 + srow];
    const unsigned short* gb = g + (size_t)batch * 131072;   // 32*8*64*8

    float rs = 0.f;
    float4 pfa[4], pfn[4];                   // in-flight stage registers (T14)

#define LOADS(t)                                              \
    {                                                         \
        const int o = (t) * 32 + c8;                          \
        pfa[0] = arow[o];      pfa[1] = arow[o + 8];          \
        pfa[2] = arow[o + 16]; pfa[3] = arow[o + 24];         \
        pfn[0] = anp[o];       pfn[1] = anp[o + 8];           \
        pfn[2] = anp[o + 16];  pfn[3] = anp[o + 24];          \
    }
    // exp+pack+write one (adjf4, anf4) pair -> P[buf] elems k*32 + c8*4
#define EW(kk, buf)                                                                  \
    {                                                                                \
        const float4 a4 = pfa[kk]; const float4 n4 = pfn[kk];                        \
        union { unsigned short u[4]; uint2 q; } wq;                                  \
        float x, p;                                                                  \
        x = asl + n4.x; p = (a4.x > 0.f) ? __expf(fmaxf(x, 0.2f * x)) : 0.f;         \
        wq.u[0] = f2bf(p); rs += __uint_as_float((unsigned)wq.u[0] << 16);           \
        x = asl + n4.y; p = (a4.y > 0.f) ? __expf(fmaxf(x, 0.2f * x)) : 0.f;         \
        wq.u[1] = f2bf(p); rs += __uint_as_float((unsigned)wq.u[1] << 16);           \
        x = asl + n4.z; p = (a4.z > 0.f) ? __expf(fmaxf(x, 0.2f * x)) : 0.f;         \
        wq.u[2] = f2bf(p); rs += __uint_as_float((unsigned)wq.u[2] << 16);           \
        x = asl + n4.w; p = (a4.w > 0.f) ? __expf(fmaxf(x, 0.2f * x)) : 0.f;         \
        wq.u[3] = f2bf(p); rs += __uint_as_float((unsigned)wq.u[3] << 16);           \
        *(uint2*)&P[buf][srow * PROW + (kk) * 32 + c8 * 4] = wq.q;                   \
    }
#define EXPWRITE(buf) { EW(0, buf) EW(1, buf) EW(2, buf) EW(3, buf) }
    // LDS-visibility barrier WITHOUT vmcnt drain: global loads stay in flight.
#define SYNC()                                                  \
    {                                                           \
        asm volatile("s_waitcnt lgkmcnt(0)" ::: "memory");      \
        __builtin_amdgcn_s_barrier();                           \
    }

    f32x4 acc[4];                            // one per 16-row tile
#pragma unroll
    for (int rt = 0; rt < 4; rt++)
#pragma unroll
        for (int i = 0; i < 4; i++) acc[rt][i] = 0.f;

    // prologue: stage phase 0
    LOADS(0)
    EXPWRITE(0)
    SYNC()

    const int li = lane & 15;
    const int kg8 = (lane >> 4) * 8;

    for (int it = 0; it < 8; ++it) {
        const int cur = it & 1;
        // 1. B-loads for this phase (oldest outstanding)
        short8v Bv[4];
#pragma unroll
        for (int kcl = 0; kcl < 4; kcl++)
            Bv[kcl] = *(const short8v*)(gb + ((size_t)((it * 4 + kcl) * 8 + wv) * 64 + lane) * 8);
        // 2. prefetch next phase's adj/an (stays in flight across barrier)
        if (it < 7) LOADS(it + 1)
        // 3. MFMA on P[cur] (ds_read A-frags; B consume waits vmcnt(8))
#pragma unroll
        for (int kcl = 0; kcl < 4; kcl++) {
#pragma unroll
            for (int rt = 0; rt < 4; rt++) {
                const short8v af = *(const short8v*)&P[cur][(rt * 16 + li) * PROW + kcl * 32 + kg8];
                acc[rt] = __builtin_amdgcn_mfma_f32_16x16x32_bf16(af, Bv[kcl], acc[rt], 0, 0, 0);
            }
        }
        // 4. stage next phase from prefetched regs
        if (it < 7) EXPWRITE(cur ^ 1)
        SYNC()
    }

    // rowsum: 8 threads per row (consecutive lanes) hold partials
    rs += __shfl_xor(rs, 1);
    rs += __shfl_xor(rs, 2);
    rs += __shfl_xor(rs, 4);
    if ((lane & 7) == 0) rtot[srow] = rs;
    __syncthreads();

    // epilogue: wave wv owns out-cols wv*16..+15 for all 64 rows
    const float bv = bvec[wv * 16 + li];
#pragma unroll
    for (int rt = 0; rt < 4; rt++) {
#pragma unroll
        for (int i = 0; i < 4; i++) {
            const int r = rt * 16 + (lane >> 4) * 4 + i;
            const float inv = 1.f / rtot[r];
            out[(size_t)(r0 + r) * HH + wv * 16 + li] = acc[rt][i] * inv + bv;
        }
    }
#undef LOADS
#undef EW
#undef EXPWRITE
#undef SYNC
}

extern "C" void kernel_launch(void* const* d_in, const int* in_sizes, int n_in,
                              void* d_out, int out_size, void* d_ws, size_t ws_size,
                              hipStream_t stream) {
    const float* X      = (const float*)d_in[0];  // M_features [B,N,F]
    const float* adj    = (const float*)d_in[1];  // M_adjacency [B,N,N]
    const float* mask   = (const float*)d_in[2];  // [B,N]
    const float* W      = (const float*)d_in[3];  // [F,H]
    const float* bvec   = (const float*)d_in[4];  // [H]
    const float* Wself  = (const float*)d_in[5];  // [H,1]
    const float* Wneigh = (const float*)d_in[6];  // [H,1]
    float* out = (float*)d_out;

    char* wsb = (char*)d_ws;
    unsigned short* g = (unsigned short*)wsb;                // 8 MB
    float* a_self  = (float*)(wsb + (size_t)BATCH * NN * HH * 2);
    float* a_neigh = a_self + (size_t)BATCH * NN;

    gat_hidden<<<(BATCH * NN) / NODES, 128, 0, stream>>>(
        X, W, Wself, Wneigh, g, a_self, a_neigh);
    gat_attend<<<512, 512, 0, stream>>>(
        adj, mask, g, a_self, a_neigh, bvec, out);
}

// Round 25
// 58.585 us; speedup vs baseline: 1.1017x; 1.0121x over previous
//
#include <hip/hip_runtime.h>
#include <math.h>

#define BATCH 32
#define NN 1024
#define FF 128
#define HH 128
#define NODES 32   // nodes per block in kernel A
#define PROW 136   // padded P-tile row (bf16) for K=128 chunks

typedef __attribute__((ext_vector_type(8))) short short8v;   // 8 bf16
typedef __attribute__((ext_vector_type(4))) float f32x4;     // MFMA acc

__device__ __forceinline__ unsigned short f2bf(float f) {    // RNE f32->bf16
    unsigned u = __float_as_uint(f);
    u += 0x7fffu + ((u >> 16) & 1u);
    return (unsigned short)(u >> 16);
}

// ---------------- Kernel A: h = X@W -> g (MFMA-B-fragment-swizzled bf16);
// a_self / a_neigh scalars.  g[(batch,kc,ct,lane=kg*16+li,e)] = h[kc*32+kg*8+e][ct*16+li]
__global__ __launch_bounds__(128) void gat_hidden(
    const float* __restrict__ X,      // [B,N,F]
    const float* __restrict__ W,      // [F,H]
    const float* __restrict__ Wself,  // [H]
    const float* __restrict__ Wneigh, // [H]
    unsigned short* __restrict__ g,   // [B][32 kc][8 ct][64 lane][8] bf16
    float* __restrict__ a_self,       // [B*N]
    float* __restrict__ a_neigh)      // [B*N]
{
    __shared__ float xs[NODES][FF];      // 16 KB
    __shared__ float hs[NODES][HH + 1];  // 16.5 KB
    const int tid = threadIdx.x;
    const long base_node = (long)blockIdx.x * NODES;
    const int batch = (int)(base_node >> 10);
    const int kc = (int)((base_node & 1023) >> 5);   // 32-node chunk index

    const float4* X4 = (const float4*)(X + base_node * FF);
    float4* xs4 = (float4*)&xs[0][0];
#pragma unroll
    for (int k = 0; k < (NODES * FF) / (4 * 128); k++)
        xs4[k * 128 + tid] = X4[k * 128 + tid];
    __syncthreads();

    float acc[NODES];
#pragma unroll
    for (int n = 0; n < NODES; n++) acc[n] = 0.f;
    const int c = tid;
    for (int fq = 0; fq < FF / 4; fq++) {
        const float w0 = W[(4 * fq + 0) * HH + c];
        const float w1 = W[(4 * fq + 1) * HH + c];
        const float w2 = W[(4 * fq + 2) * HH + c];
        const float w3 = W[(4 * fq + 3) * HH + c];
#pragma unroll
        for (int n = 0; n < NODES; n++) {
            const float4 x4 = *(const float4*)&xs[n][4 * fq];
            acc[n] += x4.x * w0 + x4.y * w1 + x4.z * w2 + x4.w * w3;
        }
    }
    {
        const int ct = c >> 4, li = c & 15;
        unsigned short* gb = g + ((((size_t)batch * 32 + kc) * 8 + ct) * 64) * 8;
        union { uint4 q; unsigned short u[8]; } pk;
#pragma unroll
        for (int kg = 0; kg < 4; kg++) {
#pragma unroll
            for (int e = 0; e < 8; e++) pk.u[e] = f2bf(acc[kg * 8 + e]);
            *(uint4*)(gb + (kg * 16 + li) * 8) = pk.q;
        }
    }
#pragma unroll
    for (int n = 0; n < NODES; n++) hs[n][c] = acc[n];
    __syncthreads();

    if (tid < 2 * NODES) {
        const int n = tid & (NODES - 1);
        const float* wvp = (tid < NODES) ? Wself : Wneigh;
        float s = 0.f;
        for (int cc = 0; cc < HH; cc++) s += hs[n][cc] * wvp[cc];
        if (tid < NODES) a_self[base_node + n] = s;
        else             a_neigh[base_node + n] = s;
    }
}

// ---------------- Kernel B: fused P@H (R24 structure) with VGPR budget fixed.
// __launch_bounds__(512, 4): grid gives only 2 blocks/CU (4 waves/SIMD), so
// let the allocator use 128 VGPRs — keeps the 2-deep adj prefetch + B-loads
// + acc live instead of collapsing the pipeline (R24 showed VGPR=64: the
// compiler was optimizing for 8 waves/SIMD the launch can never reach).
// 64-row tiles, 8 waves, wave = one ct column x 4 row-tiles, full K,
// K=128 per phase, drain-free barriers (loads span phases).
__global__ __launch_bounds__(512, 4) void gat_attend(
    const float* __restrict__ adj,     // [B,N,N]
    const float* __restrict__ mask,    // [B,N]
    const unsigned short* __restrict__ g, // swizzled bf16 h
    const float* __restrict__ a_self,  // [B*N]
    const float* __restrict__ a_neigh, // [B*N]
    const float* __restrict__ bvec,    // [H]
    float* __restrict__ out)           // [B,N,H]
{
    const int tid = threadIdx.x;
    const int lane = tid & 63;
    const int wv = tid >> 6;                 // 0..7 = ct column
    // 512 blocks; XCD x owns 4 batches
    const int b = blockIdx.x;
    const int xcd = b & 7;
    const int rest = b >> 3;                 // 0..63
    const int batch = xcd * 4 + (rest >> 4);
    const int tile = rest & 15;              // 0..15 (64-row tiles)
    const int r0 = batch * NN + tile * 64;   // 768 % 64 == 0: tile uniform

    if (mask[r0] == 0.f) {                   // invalid tile: zero-fill out
        float4* o4 = (float4*)(out + (size_t)r0 * HH);
#pragma unroll
        for (int k = 0; k < 4; k++)
            o4[k * 512 + tid] = make_float4(0.f, 0.f, 0.f, 0.f);
        return;
    }

    __shared__ unsigned short P[2][64 * PROW];   // 34816 B
    __shared__ float rtot[64];                   // 256 B

    // staging: thread owns row srow (tid>>3); per phase 16 j's:
    // j = t*128 + k*32 + c8*4 + 0..3 for k=0..3
    const int srow = tid >> 3;               // 0..63
    const int c8 = tid & 7;
    const float4* arow = (const float4*)(adj + (size_t)(r0 + srow) * NN);
    const float4* anp = (const float4*)(a_neigh + (size_t)batch * NN);
    const float asl = a_self[r0 + srow];
    const unsigned short* gb = g + (size_t)batch * 131072;   // 32*8*64*8

    float rs = 0.f;
    float4 pfa[4], pfn[4];                   // in-flight stage registers (T14)

#define LOADS(t)                                              \
    {                                                         \
        const int o = (t) * 32 + c8;                          \
        pfa[0] = arow[o];      pfa[1] = arow[o + 8];          \
        pfa[2] = arow[o + 16]; pfa[3] = arow[o + 24];         \
        pfn[0] = anp[o];       pfn[1] = anp[o + 8];           \
        pfn[2] = anp[o + 16];  pfn[3] = anp[o + 24];          \
    }
    // exp+pack+write one (adjf4, anf4) pair -> P[buf] elems k*32 + c8*4
#define EW(kk, buf)                                                                  \
    {                                                                                \
        const float4 a4 = pfa[kk]; const float4 n4 = pfn[kk];                        \
        union { unsigned short u[4]; uint2 q; } wq;                                  \
        float x, p;                                                                  \
        x = asl + n4.x; p = (a4.x > 0.f) ? __expf(fmaxf(x, 0.2f * x)) : 0.f;         \
        wq.u[0] = f2bf(p); rs += __uint_as_float((unsigned)wq.u[0] << 16);           \
        x = asl + n4.y; p = (a4.y > 0.f) ? __expf(fmaxf(x, 0.2f * x)) : 0.f;         \
        wq.u[1] = f2bf(p); rs += __uint_as_float((unsigned)wq.u[1] << 16);           \
        x = asl + n4.z; p = (a4.z > 0.f) ? __expf(fmaxf(x, 0.2f * x)) : 0.f;         \
        wq.u[2] = f2bf(p); rs += __uint_as_float((unsigned)wq.u[2] << 16);           \
        x = asl + n4.w; p = (a4.w > 0.f) ? __expf(fmaxf(x, 0.2f * x)) : 0.f;         \
        wq.u[3] = f2bf(p); rs += __uint_as_float((unsigned)wq.u[3] << 16);           \
        *(uint2*)&P[buf][srow * PROW + (kk) * 32 + c8 * 4] = wq.q;                   \
    }
#define EXPWRITE(buf) { EW(0, buf) EW(1, buf) EW(2, buf) EW(3, buf) }
    // LDS-visibility barrier WITHOUT vmcnt drain: global loads stay in flight.
#define SYNC()                                                  \
    {                                                           \
        asm volatile("s_waitcnt lgkmcnt(0)" ::: "memory");      \
        __builtin_amdgcn_s_barrier();                           \
    }

    f32x4 acc[4];                            // one per 16-row tile
#pragma unroll
    for (int rt = 0; rt < 4; rt++)
#pragma unroll
        for (int i = 0; i < 4; i++) acc[rt][i] = 0.f;

    // prologue: stage phase 0
    LOADS(0)
    EXPWRITE(0)
    SYNC()

    const int li = lane & 15;
    const int kg8 = (lane >> 4) * 8;

    for (int it = 0; it < 8; ++it) {
        const int cur = it & 1;
        // 1. B-loads for this phase (oldest outstanding)
        short8v Bv[4];
#pragma unroll
        for (int kcl = 0; kcl < 4; kcl++)
            Bv[kcl] = *(const short8v*)(gb + ((size_t)((it * 4 + kcl) * 8 + wv) * 64 + lane) * 8);
        // 2. prefetch next phase's adj/an (stays in flight across barrier)
        if (it < 7) LOADS(it + 1)
        // 3. MFMA on P[cur] (ds_read A-frags; B consume leaves adj in flight)
#pragma unroll
        for (int kcl = 0; kcl < 4; kcl++) {
#pragma unroll
            for (int rt = 0; rt < 4; rt++) {
                const short8v af = *(const short8v*)&P[cur][(rt * 16 + li) * PROW + kcl * 32 + kg8];
                acc[rt] = __builtin_amdgcn_mfma_f32_16x16x32_bf16(af, Bv[kcl], acc[rt], 0, 0, 0);
            }
        }
        // 4. stage next phase from prefetched regs
        if (it < 7) EXPWRITE(cur ^ 1)
        SYNC()
    }

    // rowsum: 8 threads per row (consecutive lanes) hold partials
    rs += __shfl_xor(rs, 1);
    rs += __shfl_xor(rs, 2);
    rs += __shfl_xor(rs, 4);
    if ((lane & 7) == 0) rtot[srow] = rs;
    __syncthreads();

    // epilogue: wave wv owns out-cols wv*16..+15 for all 64 rows
    const float bv = bvec[wv * 16 + li];
#pragma unroll
    for (int rt = 0; rt < 4; rt++) {
#pragma unroll
        for (int i = 0; i < 4; i++) {
            const int r = rt * 16 + (lane >> 4) * 4 + i;
            const float inv = 1.f / rtot[r];
            out[(size_t)(r0 + r) * HH + wv * 16 + li] = acc[rt][i] * inv + bv;
        }
    }
#undef LOADS
#undef EW
#undef EXPWRITE
#undef SYNC
}

extern "C" void kernel_launch(void* const* d_in, const int* in_sizes, int n_in,
                              void* d_out, int out_size, void* d_ws, size_t ws_size,
                              hipStream_t stream) {
    const float* X      = (const float*)d_in[0];  // M_features [B,N,F]
    const float* adj    = (const float*)d_in[1];  // M_adjacency [B,N,N]
    const float* mask   = (const float*)d_in[2];  // [B,N]
    const float* W      = (const float*)d_in[3];  // [F,H]
    const float* bvec   = (const float*)d_in[4];  // [H]
    const float* Wself  = (const float*)d_in[5];  // [H,1]
    const float* Wneigh = (const float*)d_in[6];  // [H,1]
    float* out = (float*)d_out;

    char* wsb = (char*)d_ws;
    unsigned short* g = (unsigned short*)wsb;                // 8 MB
    float* a_self  = (float*)(wsb + (size_t)BATCH * NN * HH * 2);
    float* a_neigh = a_self + (size_t)BATCH * NN;

    gat_hidden<<<(BATCH * NN) / NODES, 128, 0, stream>>>(
        X, W, Wself, Wneigh, g, a_self, a_neigh);
    gat_attend<<<512, 512, 0, stream>>>(
        adj, mask, g, a_self, a_neigh, bvec, out);
}